// Round 3
// baseline (659.499 us; speedup 1.0000x reference)
//
#include <hip/hip_runtime.h>
#include <hip/hip_bf16.h>
#include <stdint.h>

#define T_SEQ 2048
#define NHEADS 16
#define HDIM 64
#define DMODEL 1024
#define BATCH 4
#define MROWS (BATCH * T_SEQ)   // 8192

typedef __attribute__((ext_vector_type(8))) short bf16x8;
typedef __attribute__((ext_vector_type(4))) float f32x4;

typedef const __attribute__((address_space(1))) void* gas_t;
typedef __attribute__((address_space(3))) void* las_t;

__device__ __forceinline__ f32x4 mfma_16x16x32(bf16x8 a, bf16x8 b, f32x4 c) {
  return __builtin_amdgcn_mfma_f32_16x16x32_bf16(a, b, c, 0, 0, 0);
}

__device__ __forceinline__ unsigned short f2bf(float f) {
  union { float f; unsigned u; } v; v.f = f;
  unsigned r = v.u + 0x7FFFu + ((v.u >> 16) & 1u);  // RNE
  return (unsigned short)(r >> 16);
}
__device__ __forceinline__ float bf2f(unsigned short h) {
  union { unsigned u; float f; } v; v.u = ((unsigned)h) << 16;
  return v.f;
}

// ---------------- conversion kernels ----------------

// fp32 -> bf16, 4 elems/thread, exact grid
__global__ void k_cvt_x(const float* __restrict__ in, unsigned short* __restrict__ out) {
  int i = blockIdx.x * blockDim.x + threadIdx.x;
  float4 v = reinterpret_cast<const float4*>(in)[i];
  ushort4 o;
  o.x = f2bf(v.x); o.y = f2bf(v.y); o.z = f2bf(v.z); o.w = f2bf(v.w);
  reinterpret_cast<ushort4*>(out)[i] = o;
}

// in [K][N] fp32 -> out [N][K] bf16  (B^T layout for GEMM)
__global__ void k_cvt_t(const float* __restrict__ in, unsigned short* __restrict__ out,
                        int K, int N) {
  __shared__ float tile[32][33];
  int n0 = blockIdx.x * 32, k0 = blockIdx.y * 32;
  int tx = threadIdx.x, ty = threadIdx.y;  // block (32,8)
#pragma unroll
  for (int i = 0; i < 32; i += 8)
    tile[ty + i][tx] = in[(size_t)(k0 + ty + i) * N + n0 + tx];
  __syncthreads();
#pragma unroll
  for (int i = 0; i < 32; i += 8)
    out[(size_t)(n0 + ty + i) * K + k0 + tx] = f2bf(tile[tx][ty + i]);
}

// ---------------- GEMM (m97 structure: 128x128 tile, BK=64, global_load_lds) ----------------
// C[M,N] = A[M,K] @ Bt[N,K]^T + bias
// MODE 0: QKV epilogue -> scatter to Q[BH,T,64], K[BH,T,64], Vt[BH,64,T] (bf16)
// MODE 1: fp32 linear output + bias
template <int MODE>
__launch_bounds__(256, 2)
__global__ void k_gemm(const unsigned short* __restrict__ A,
                       const unsigned short* __restrict__ Bt,
                       const float* __restrict__ bias,
                       unsigned short* __restrict__ o_q,
                       unsigned short* __restrict__ o_k,
                       unsigned short* __restrict__ o_vt,
                       float* __restrict__ o_f,
                       int Ksz, int Nsz) {
  __shared__ __align__(16) unsigned short As[128 * 64];
  __shared__ __align__(16) unsigned short Bs[128 * 64];
  const int tid = threadIdx.x;
  const int w = tid >> 6, lane = tid & 63;
  const int wr = w >> 1, wc = w & 1;          // 2x2 wave grid, each wave 64x64
  const int lr = lane & 15, lg = lane >> 4;
  const int brow = blockIdx.y * 128, bcol = blockIdx.x * 128;
  const int srow = lane >> 3, scol = (lane & 7) * 8;  // staging: 8 lanes/row, 16B each

  f32x4 acc[4][4] = {};

  for (int k0 = 0; k0 < Ksz; k0 += 64) {
#pragma unroll
    for (int j = 0; j < 4; ++j) {
      int chunk = w * 4 + j;                 // 16 chunks of 8 rows x 64 cols
      int row = chunk * 8 + srow;
      const unsigned short* ga = A + (size_t)(brow + row) * Ksz + k0 + scol;
      const unsigned short* gb = Bt + (size_t)(bcol + row) * Ksz + k0 + scol;
      // wave-uniform LDS base + lane*16 == linear row-major [128][64] layout
      __builtin_amdgcn_global_load_lds((gas_t)ga, (las_t)&As[chunk * 512], 16, 0, 0);
      __builtin_amdgcn_global_load_lds((gas_t)gb, (las_t)&Bs[chunk * 512], 16, 0, 0);
    }
    __syncthreads();
#pragma unroll
    for (int kk = 0; kk < 2; ++kk) {
      bf16x8 af[4], bb[4];
#pragma unroll
      for (int m = 0; m < 4; ++m)
        af[m] = *reinterpret_cast<const bf16x8*>(
            &As[(wr * 64 + m * 16 + lr) * 64 + kk * 32 + lg * 8]);
#pragma unroll
      for (int n = 0; n < 4; ++n)
        bb[n] = *reinterpret_cast<const bf16x8*>(
            &Bs[(wc * 64 + n * 16 + lr) * 64 + kk * 32 + lg * 8]);
#pragma unroll
      for (int m = 0; m < 4; ++m)
#pragma unroll
        for (int n = 0; n < 4; ++n)
          acc[m][n] = mfma_16x16x32(af[m], bb[n], acc[m][n]);
    }
    __syncthreads();
  }

  // epilogue: C/D layout col=lane&15, row=(lane>>4)*4+reg  [m89-verified]
#pragma unroll
  for (int n = 0; n < 4; ++n) {
    int c = bcol + wc * 64 + n * 16 + lr;
    float bv = bias[c];
#pragma unroll
    for (int m = 0; m < 4; ++m) {
#pragma unroll
      for (int r = 0; r < 4; ++r) {
        int row = brow + wr * 64 + m * 16 + lg * 4 + r;
        float val = acc[m][n][r] + bv;
        if constexpr (MODE == 0) {
          int which = c >> 10;           // 0:q 1:k 2:v
          int h = (c >> 6) & 15, d = c & 63;
          int b = row >> 11, t = row & 2047;
          int bh = b * NHEADS + h;
          if (which == 0)
            o_q[((size_t)bh * T_SEQ + t) * HDIM + d] = f2bf(val);
          else if (which == 1)
            o_k[((size_t)bh * T_SEQ + t) * HDIM + d] = f2bf(val);
          else
            o_vt[((size_t)bh * HDIM + d) * T_SEQ + t] = f2bf(val);
        } else {
          o_f[(size_t)row * Nsz + c] = val;
        }
      }
    }
  }
}

// ---------------- flash attention ----------------
// grid (T/64, B*H), 4 waves/block, wave = 16 q-rows, key-block = 32.
// No __syncthreads: waves fully independent (wave-private LDS P-tile).
__launch_bounds__(256, 4)
__global__ void k_attn(const unsigned short* __restrict__ Q,
                       const unsigned short* __restrict__ K,
                       const unsigned short* __restrict__ Vt,
                       unsigned short* __restrict__ Yb) {
  __shared__ __align__(16) unsigned short Plds[4][512];  // per-wave 16x32 bf16
  const int tid = threadIdx.x;
  const int w = tid >> 6, lane = tid & 63;
  const int lr = lane & 15, lg = lane >> 4;
  const int bh = blockIdx.y;
  const int qblk = gridDim.x - 1 - blockIdx.x;  // long causal rows launch first
  const int q0 = qblk * 64 + w * 16;
  const unsigned short* Qh = Q + (size_t)bh * T_SEQ * HDIM;
  const unsigned short* Kh = K + (size_t)bh * T_SEQ * HDIM;
  const unsigned short* Vh = Vt + (size_t)bh * HDIM * T_SEQ;

  // Q fragments, pre-scaled by 1/sqrt(64)=0.125 (exact in bf16)
  bf16x8 aq[2];
#pragma unroll
  for (int kk = 0; kk < 2; ++kk) {
    bf16x8 v = *reinterpret_cast<const bf16x8*>(&Qh[(size_t)(q0 + lr) * HDIM + kk * 32 + lg * 8]);
#pragma unroll
    for (int j = 0; j < 8; ++j)
      v[j] = (short)f2bf(bf2f((unsigned short)v[j]) * 0.125f);
    aq[kk] = v;
  }

  f32x4 o[4] = {};
  float mrow[4], lrow[4];
#pragma unroll
  for (int r = 0; r < 4; ++r) { mrow[r] = -__builtin_huge_valf(); lrow[r] = 0.f; }

  const int nkb = (q0 + 15) / 32 + 1;
  unsigned short* pl = &Plds[w][0];

  for (int kb = 0; kb < nkb; ++kb) {
    const int kbase = kb * 32;
    // S = (Q*0.125) @ K^T : two 16x16 tiles over 32 keys
    f32x4 s[2];
#pragma unroll
    for (int st = 0; st < 2; ++st) {
      f32x4 a = {};
#pragma unroll
      for (int kk = 0; kk < 2; ++kk) {
        bf16x8 bk = *reinterpret_cast<const bf16x8*>(
            &Kh[(size_t)(kbase + st * 16 + lr) * HDIM + kk * 32 + lg * 8]);
        a = mfma_16x16x32(aq[kk], bk, a);
      }
      s[st] = a;
    }
    // causal mask
    if (kbase + 31 > q0) {
#pragma unroll
      for (int st = 0; st < 2; ++st) {
        int key = kbase + st * 16 + lr;
#pragma unroll
        for (int r = 0; r < 4; ++r) {
          int q = q0 + lg * 4 + r;
          if (key > q) s[st][r] = -__builtin_huge_valf();
        }
      }
    }
    // online softmax (reduce across the 16 lanes sharing lg)
    float alpha[4];
    unsigned short pb0[4], pb1[4];
#pragma unroll
    for (int r = 0; r < 4; ++r) {
      float tm = fmaxf(s[0][r], s[1][r]);
#pragma unroll
      for (int off = 1; off < 16; off <<= 1) tm = fmaxf(tm, __shfl_xor(tm, off));
      float newm = fmaxf(mrow[r], tm);
      alpha[r] = __expf(mrow[r] - newm);
      mrow[r] = newm;
      float p0 = __expf(s[0][r] - newm);
      float p1 = __expf(s[1][r] - newm);
      float ps = p0 + p1;
#pragma unroll
      for (int off = 1; off < 16; off <<= 1) ps += __shfl_xor(ps, off);
      lrow[r] = lrow[r] * alpha[r] + ps;
      pb0[r] = f2bf(p0);
      pb1[r] = f2bf(p1);
    }
    // P -> LDS (XOR-swizzled row-major [16][32] bf16), wave-private
#pragma unroll
    for (int r = 0; r < 4; ++r) {
      int q = lg * 4 + r;
      int sw = (q & 7) << 4;
      *(unsigned short*)((char*)pl + (((q * 32 + lr) * 2) ^ sw)) = pb0[r];
      *(unsigned short*)((char*)pl + (((q * 32 + 16 + lr) * 2) ^ sw)) = pb1[r];
    }
    // A-fragment read back (compiler inserts lgkmcnt; same-wave dependency)
    bf16x8 pa = *(const bf16x8*)((const char*)pl + ((lr * 64 + lg * 16) ^ ((lr & 7) << 4)));
    // rescale O and accumulate PV over 4 d-tiles
#pragma unroll
    for (int dt = 0; dt < 4; ++dt) {
      f32x4 t = o[dt];
#pragma unroll
      for (int r = 0; r < 4; ++r) t[r] *= alpha[r];
      bf16x8 bv = *reinterpret_cast<const bf16x8*>(
          &Vh[(size_t)(dt * 16 + lr) * T_SEQ + kbase + lg * 8]);
      o[dt] = mfma_16x16x32(pa, bv, t);
    }
  }

  // normalize + write y in [B,T,C] bf16 layout (input to proj GEMM)
  const int b = bh >> 4, h = bh & 15;
#pragma unroll
  for (int r = 0; r < 4; ++r) {
    float inv = 1.0f / lrow[r];
    int q = q0 + lg * 4 + r;
    size_t base = ((size_t)b * T_SEQ + q) * DMODEL + h * HDIM;
#pragma unroll
    for (int dt = 0; dt < 4; ++dt)
      Yb[base + dt * 16 + lr] = f2bf(o[dt][r] * inv);
  }
}

// ---------------- launch ----------------
extern "C" void kernel_launch(void* const* d_in, const int* in_sizes, int n_in,
                              void* d_out, int out_size, void* d_ws, size_t ws_size,
                              hipStream_t stream) {
  const float* x      = (const float*)d_in[0];
  const float* w_qkv  = (const float*)d_in[1];
  const float* b_qkv  = (const float*)d_in[2];
  const float* w_proj = (const float*)d_in[3];
  const float* b_proj = (const float*)d_in[4];
  float* out = (float*)d_out;

  char* ws = (char*)d_ws;
  size_t off = 0;
  unsigned short* xb     = (unsigned short*)(ws + off); off += (size_t)MROWS * DMODEL * 2;       // 16 MB
  unsigned short* wqkvT  = (unsigned short*)(ws + off); off += (size_t)3 * DMODEL * DMODEL * 2;  // 6 MB
  unsigned short* wprojT = (unsigned short*)(ws + off); off += (size_t)DMODEL * DMODEL * 2;      // 2 MB
  unsigned short* Qb     = (unsigned short*)(ws + off); off += (size_t)64 * T_SEQ * HDIM * 2;    // 16 MB
  unsigned short* Kb     = (unsigned short*)(ws + off); off += (size_t)64 * T_SEQ * HDIM * 2;    // 16 MB
  unsigned short* Vt     = (unsigned short*)(ws + off); off += (size_t)64 * T_SEQ * HDIM * 2;    // 16 MB
  // Yb aliases xb: xb is dead after GEMM1 (stream-ordered before k_attn writes Yb).
  unsigned short* Yb     = xb;

  // weights -> bf16 transposed (B^T layout)
  k_cvt_t<<<dim3(3 * DMODEL / 32, DMODEL / 32), dim3(32, 8), 0, stream>>>(w_qkv, wqkvT, DMODEL, 3 * DMODEL);
  k_cvt_t<<<dim3(DMODEL / 32, DMODEL / 32), dim3(32, 8), 0, stream>>>(w_proj, wprojT, DMODEL, DMODEL);
  // x -> bf16 (8192x1024)
  k_cvt_x<<<(MROWS * DMODEL) / (256 * 4), 256, 0, stream>>>(x, xb);
  // QKV GEMM: [8192,1024] @ [1024,3072] -> scatter Q/K/Vt
  k_gemm<0><<<dim3(3 * DMODEL / 128, MROWS / 128), 256, 0, stream>>>(
      xb, wqkvT, b_qkv, Qb, Kb, Vt, nullptr, DMODEL, 3 * DMODEL);
  // flash attention -> Yb [8192,1024] bf16
  k_attn<<<dim3(T_SEQ / 64, BATCH * NHEADS), 256, 0, stream>>>(Qb, Kb, Vt, Yb);
  // proj GEMM: [8192,1024] @ [1024,1024] + bias -> fp32 out
  k_gemm<1><<<dim3(DMODEL / 128, MROWS / 128), 256, 0, stream>>>(
      Yb, wprojT, b_proj, nullptr, nullptr, nullptr, out, DMODEL, DMODEL);
}